// Round 3
// baseline (268.201 us; speedup 1.0000x reference)
//
#include <hip/hip_runtime.h>
#include <hip/hip_bf16.h>

typedef __bf16 bf16x8 __attribute__((ext_vector_type(8)));
typedef __bf16 bf16x4 __attribute__((ext_vector_type(4)));
typedef float  f32x4  __attribute__((ext_vector_type(4)));

#define S_LEN 2048
#define DH    64
#define QB    128
#define KVB   64

// Swizzled LDS element offset for a [rows][64] bf16 tile (128B row stride).
__device__ __forceinline__ int swz(int row, int col) {
    return (row << 6) + ((((col >> 3) ^ row) & 7) << 3) + (col & 7);
}

__launch_bounds__(256, 4)   // cap VGPR at 128 -> 16 waves/CU possible
__global__ void attn_fwd(const float* __restrict__ Kg,
                         const float* __restrict__ Qg,
                         const float* __restrict__ Vg,
                         float* __restrict__ Og) {
    __shared__ __bf16 Klds[2][64 * 64];   // [kv][d]                swizzled
    __shared__ __bf16 Vlds[2][64 * 64];   // [d][slot], kv=pi(slot) swizzled

    const int qb  = blockIdx.x;
    const int bh  = blockIdx.y;
    const int tid = threadIdx.x;
    const int w   = tid >> 6;
    const int l   = tid & 63;
    const int lo  = l & 15;
    const int hi  = l >> 4;

    const int    q0   = qb * QB;
    const size_t base = (size_t)bh * S_LEN * DH;
    const float* Kb = Kg + base;
    const float* Qb = Qg + base;
    const float* Vb = Vg + base;
    float*       Ob = Og + base;

    // ---- Q fragments, two 16-row groups per wave; scale 1/8 folded in ----
    bf16x8 bq[2][2];
    #pragma unroll
    for (int g = 0; g < 2; ++g) {
        const int qrow = q0 + w * 32 + g * 16 + lo;
        #pragma unroll
        for (int dc = 0; dc < 2; ++dc) {
            const float* p = Qb + (size_t)qrow * DH + dc * 32 + hi * 8;
            f32x4 v0 = *(const f32x4*)p;
            f32x4 v1 = *(const f32x4*)(p + 4);
            #pragma unroll
            for (int j = 0; j < 4; ++j) {
                bq[g][dc][j]     = (__bf16)(v0[j] * 0.125f);
                bq[g][dc][j + 4] = (__bf16)(v1[j] * 0.125f);
            }
        }
    }

    f32x4 oacc[2][4];
    #pragma unroll
    for (int g = 0; g < 2; ++g)
        #pragma unroll
        for (int n = 0; n < 4; ++n) oacc[g][n] = (f32x4){0.f, 0.f, 0.f, 0.f};
    float mrow[2] = {-1e30f, -1e30f}, lrow[2] = {0.f, 0.f};

    // staging index precompute
    const int krr = tid >> 4;          // K rows
    const int kc4 = (tid & 15) * 4;    // K cols
    const int u0  = w * 2, u1 = w * 2 + 1;
    const int kvb0 = (u0 >> 2) * 32 + (u0 & 3) * 4;   // V pi-permutation bases
    const int kvb1 = (u1 >> 2) * 32 + (u1 & 3) * 4;

    const int nt = 2 * qb + 2;

    // staging registers (live across compute: T14 async-stage split)
    f32x4 kregv[4];
    float vreg[16];

    auto load_tile = [&](int t) {
        const int kv0 = t * KVB;
        const float* kp = Kb + (size_t)kv0 * DH + kc4;
        #pragma unroll
        for (int i = 0; i < 4; ++i)
            kregv[i] = *(const f32x4*)(kp + (size_t)(i * 16 + krr) * DH);
        const float* vp0 = Vb + (size_t)(kv0 + kvb0) * DH + l;
        const float* vp1 = Vb + (size_t)(kv0 + kvb1) * DH + l;
        #pragma unroll
        for (int i = 0; i < 8; ++i) {
            const int ci = (i >> 2) * 16 + (i & 3);   // within-base kv offset
            vreg[i]     = vp0[(size_t)ci * DH];
            vreg[i + 8] = vp1[(size_t)ci * DH];
        }
    };
    auto store_tile = [&](int buf) {
        #pragma unroll
        for (int i = 0; i < 4; ++i) {
            bf16x4 kb;
            #pragma unroll
            for (int j = 0; j < 4; ++j) kb[j] = (__bf16)kregv[i][j];
            *(bf16x4*)&Klds[buf][swz(i * 16 + krr, kc4)] = kb;
        }
        bf16x8 v0, v1;
        #pragma unroll
        for (int i = 0; i < 8; ++i) { v0[i] = (__bf16)vreg[i]; v1[i] = (__bf16)vreg[i + 8]; }
        *(bf16x8*)&Vlds[buf][swz(l, w * 16)]     = v0;
        *(bf16x8*)&Vlds[buf][swz(l, w * 16 + 8)] = v1;
    };

    // prologue: stage tile 0
    load_tile(0);
    store_tile(0);
    __syncthreads();

    for (int t = 0; t < nt; ++t) {
        const int  cur  = t & 1;
        const bool more = (t + 1 < nt);
        if (more) load_tile(t + 1);          // issue early; consumed after compute

        #pragma unroll
        for (int g = 0; g < 2; ++g) {
            const int dd = 8 * qb + 2 * w + g - 4 * t;   // diagonal sub-block idx
            if (dd < 0) continue;                         // fully masked: skip
            const int cmax = dd < 4 ? dd + 1 : 4;

            // ---- S^T = K (Q*scale)^T ----
            f32x4 sc[4];
            __builtin_amdgcn_s_setprio(1);
            #pragma unroll
            for (int c = 0; c < 4; ++c) {
                if (c < cmax) {
                    f32x4 acc = (f32x4){0.f, 0.f, 0.f, 0.f};
                    #pragma unroll
                    for (int dc = 0; dc < 2; ++dc) {
                        bf16x8 ak = *(const bf16x8*)&Klds[cur][swz(c * 16 + lo, dc * 32 + hi * 8)];
                        acc = __builtin_amdgcn_mfma_f32_16x16x32_bf16(ak, bq[g][dc], acc, 0, 0, 0);
                    }
                    sc[c] = acc;
                } else {
                    sc[c] = (f32x4){-1e30f, -1e30f, -1e30f, -1e30f};
                }
            }
            __builtin_amdgcn_s_setprio(0);

            // causal mask on the diagonal 16x16 sub-block
            if (dd < 4) {
                #pragma unroll
                for (int r = 0; r < 4; ++r)
                    if (hi * 4 + r > lo) sc[dd][r] = -1e30f;
            }

            // ---- online softmax (q-column lane-local; 4-lane-group reduce) ----
            float pm = -1e30f;
            #pragma unroll
            for (int c = 0; c < 4; ++c)
                #pragma unroll
                for (int r = 0; r < 4; ++r) pm = fmaxf(pm, sc[c][r]);
            pm = fmaxf(pm, __shfl_xor(pm, 16, 64));
            pm = fmaxf(pm, __shfl_xor(pm, 32, 64));

            const float mn = fmaxf(mrow[g], pm);
            const float fr = __expf(mrow[g] - mn);
            mrow[g] = mn;
            float rs = 0.f;
            #pragma unroll
            for (int c = 0; c < 4; ++c)
                #pragma unroll
                for (int r = 0; r < 4; ++r) {
                    float p = __expf(sc[c][r] - mn);
                    sc[c][r] = p;
                    rs += p;
                }
            rs += __shfl_xor(rs, 16, 64);
            rs += __shfl_xor(rs, 32, 64);
            lrow[g] = lrow[g] * fr + rs;
            #pragma unroll
            for (int n = 0; n < 4; ++n) oacc[g][n] *= fr;

            // ---- pack P^T into PV B-fragments (pi-consistent with Vlds) ----
            bf16x8 pb[2];
            #pragma unroll
            for (int kc = 0; kc < 2; ++kc)
                #pragma unroll
                for (int j = 0; j < 8; ++j)
                    pb[kc][j] = (__bf16)sc[kc * 2 + (j >> 2)][j & 3];

            // ---- O^T += V^T P^T (skip upper-kv half when fully masked) ----
            __builtin_amdgcn_s_setprio(1);
            #pragma unroll
            for (int n = 0; n < 4; ++n) {
                bf16x8 av0 = *(const bf16x8*)&Vlds[cur][swz(n * 16 + lo, hi * 8)];
                oacc[g][n] = __builtin_amdgcn_mfma_f32_16x16x32_bf16(av0, pb[0], oacc[g][n], 0, 0, 0);
            }
            if (cmax > 2) {
                #pragma unroll
                for (int n = 0; n < 4; ++n) {
                    bf16x8 av1 = *(const bf16x8*)&Vlds[cur][swz(n * 16 + lo, 32 + hi * 8)];
                    oacc[g][n] = __builtin_amdgcn_mfma_f32_16x16x32_bf16(av1, pb[1], oacc[g][n], 0, 0, 0);
                }
            }
            __builtin_amdgcn_s_setprio(0);
        }

        if (more) store_tile((t + 1) & 1);   // vmcnt drain + cvt + ds_write late
        __syncthreads();                      // one barrier per tile
    }

    // ---- epilogue ----
    #pragma unroll
    for (int g = 0; g < 2; ++g) {
        const float linv = 1.0f / lrow[g];
        const int   q    = q0 + w * 32 + g * 16 + lo;
        #pragma unroll
        for (int n = 0; n < 4; ++n) {
            f32x4 o;
            #pragma unroll
            for (int r = 0; r < 4; ++r) o[r] = oacc[g][n][r] * linv;
            *(f32x4*)(Ob + (size_t)q * DH + n * 16 + hi * 4) = o;
        }
    }
}

extern "C" void kernel_launch(void* const* d_in, const int* in_sizes, int n_in,
                              void* d_out, int out_size, void* d_ws, size_t ws_size,
                              hipStream_t stream) {
    const float* keys    = (const float*)d_in[0];
    const float* queries = (const float*)d_in[1];
    const float* values  = (const float*)d_in[2];
    float* out = (float*)d_out;

    const int BH = in_sizes[0] / (S_LEN * DH);   // B*H = 64
    dim3 grid(S_LEN / QB, BH);
    dim3 block(256);
    attn_fwd<<<grid, block, 0, stream>>>(keys, queries, values, out);
}

// Round 4
// 153.340 us; speedup vs baseline: 1.7491x; 1.7491x over previous
//
#include <hip/hip_runtime.h>
#include <hip/hip_bf16.h>

typedef __bf16 bf16x8 __attribute__((ext_vector_type(8)));
typedef __bf16 bf16x4 __attribute__((ext_vector_type(4)));
typedef float  f32x4  __attribute__((ext_vector_type(4)));

#define S_LEN 2048
#define DH    64
#define QB    64
#define KVB   64
#define NT    (S_LEN / KVB)     // 32 KV tiles
#define TILE_ELEMS 8192         // bf16 elems per (K+V) tile blob: 2 x 4096
#define TILE_BYTES 16384
#define L2E   1.44269504088896f

// Swizzled LDS element offset for a [rows][64] bf16 tile (128B row stride).
__device__ __forceinline__ int swz(int row, int col) {
    return (row << 6) + ((((col >> 3) ^ row) & 7) << 3) + (col & 7);
}

__device__ __forceinline__ void gl2lds16(const void* g, void* l) {
    __builtin_amdgcn_global_load_lds(
        (const __attribute__((address_space(1))) void*)g,
        (__attribute__((address_space(3))) void*)l, 16, 0, 0);
}

// ---------------------------------------------------------------------------
// Prep: fp32 K/V -> bf16 pre-swizzled LDS-image blobs, one 16KB blob per
// (bh, kv-tile).  K image [kv][d] swizzled; V image [d][slot] (kv=pi(slot)),
// transposed via LDS, swizzled.  Done ONCE per element (vs 16.5x in-kernel).
// ---------------------------------------------------------------------------
__launch_bounds__(256, 4)
__global__ void prep_kv(const float* __restrict__ Kg,
                        const float* __restrict__ Vg,
                        __bf16* __restrict__ blob) {
    __shared__ __bf16 Vtmp[64 * 72];          // padded stride: bank-spread
    const int bt  = blockIdx.x;               // bh*32 + t
    const int tid = threadIdx.x;
    const size_t gbase = (size_t)bt * (KVB * DH);   // (bh*S + t*64)*DH
    const float* Kt = Kg + gbase;
    const float* Vt = Vg + gbase;
    __bf16* outK = blob + (size_t)bt * TILE_ELEMS;
    __bf16* outV = outK + 4096;

    // ---- K image: 2 out 16B-chunks per thread, reads row-permuted (XOR) ----
    #pragma unroll
    for (int u = 0; u < 2; ++u) {
        const int m   = tid * 2 + u;          // out chunk 0..511
        const int row = m >> 3, cc = m & 7;
        const int c   = cc ^ (row & 7);       // source col-chunk
        const float* src = Kt + row * DH + c * 8;
        f32x4 a = *(const f32x4*)src;
        f32x4 b = *(const f32x4*)(src + 4);
        bf16x8 o;
        #pragma unroll
        for (int j = 0; j < 4; ++j) { o[j] = (__bf16)a[j]; o[j + 4] = (__bf16)b[j]; }
        *(bf16x8*)&outK[m * 8] = o;
    }

    // ---- V: stage tile to LDS (bf16, stride 72 elems) ----
    {
        const int kv = tid >> 2, dq = (tid & 3) * 16;
        const float* src = Vt + kv * DH + dq;
        f32x4 v0 = *(const f32x4*)src,        v1 = *(const f32x4*)(src + 4);
        f32x4 v2 = *(const f32x4*)(src + 8),  v3 = *(const f32x4*)(src + 12);
        bf16x8 o0, o1;
        #pragma unroll
        for (int j = 0; j < 4; ++j) {
            o0[j] = (__bf16)v0[j]; o0[j + 4] = (__bf16)v1[j];
            o1[j] = (__bf16)v2[j]; o1[j + 4] = (__bf16)v3[j];
        }
        *(bf16x8*)&Vtmp[kv * 72 + dq]     = o0;
        *(bf16x8*)&Vtmp[kv * 72 + dq + 8] = o1;
    }
    __syncthreads();

    // ---- V image: transpose + pi-permute + swizzle ----
    #pragma unroll
    for (int u = 0; u < 2; ++u) {
        const int m  = tid * 2 + u;
        const int d  = m >> 3, cc = m & 7;
        const int S8 = cc ^ (d & 7);          // slot-group s>>3
        const int kc = S8 >> 2, hs = S8 & 3;
        bf16x8 o;
        #pragma unroll
        for (int j = 0; j < 8; ++j) {
            const int kv = (kc * 2 + (j >> 2)) * 16 + hs * 4 + (j & 3);  // pi
            o[j] = Vtmp[kv * 72 + d];
        }
        *(bf16x8*)&outV[m * 8] = o;
    }
}

// ---------------------------------------------------------------------------
// Attention main kernel: blob-staged, double-buffered 2-phase.
// ---------------------------------------------------------------------------
__launch_bounds__(256, 4)
__global__ void attn_fwd2(const float* __restrict__ Qg,
                          float* __restrict__ Og,
                          const __bf16* __restrict__ blob) {
    __shared__ __bf16 Klds[2][4096];   // [kv][d] swizzled image
    __shared__ __bf16 Vlds[2][4096];   // [d][slot] pi+swizzled image

    const int qb  = blockIdx.x;
    const int bh  = blockIdx.y;
    const int tid = threadIdx.x;
    const int w   = tid >> 6;
    const int l   = tid & 63;
    const int lo  = l & 15;
    const int hi  = l >> 4;

    const int    q0   = qb * QB;
    const size_t base = (size_t)bh * S_LEN * DH;
    const float* Qb = Qg + base;
    float*       Ob = Og + base;
    const char*  blobB = (const char*)(blob + (size_t)bh * NT * TILE_ELEMS);

    // ---- Q fragments (B-operand of swapped QK^T); scale 1/8 exact ----
    bf16x8 bq[2];
    {
        const int qrow = q0 + w * 16 + lo;
        #pragma unroll
        for (int dc = 0; dc < 2; ++dc) {
            const float* p = Qb + (size_t)qrow * DH + dc * 32 + hi * 8;
            f32x4 v0 = *(const f32x4*)p;
            f32x4 v1 = *(const f32x4*)(p + 4);
            #pragma unroll
            for (int j = 0; j < 4; ++j) {
                bq[dc][j]     = (__bf16)(v0[j] * 0.125f);
                bq[dc][j + 4] = (__bf16)(v1[j] * 0.125f);
            }
        }
    }

    f32x4 oacc[4];
    #pragma unroll
    for (int n = 0; n < 4; ++n) oacc[n] = (f32x4){0.f, 0.f, 0.f, 0.f};
    float mrow = -1e30f, lrow = 0.f;

    // wave-quarter staging: 4 x global_load_lds_dwordx4, zero VALU staging
    auto stage = [&](int buf, int t) {
        const char* tb = blobB + (size_t)t * TILE_BYTES;
        char* kd = (char*)&Klds[buf][w * 1024];
        char* vd = (char*)&Vlds[buf][w * 1024];
        const char* ks = tb + w * 2048 + l * 16;
        const char* vs = tb + 8192 + w * 2048 + l * 16;
        gl2lds16(ks,        kd);
        gl2lds16(ks + 1024, kd + 1024);
        gl2lds16(vs,        vd);
        gl2lds16(vs + 1024, vd + 1024);
    };

    stage(0, 0);
    __syncthreads();                       // drain vmcnt + barrier

    for (int t = 0; t <= qb; ++t) {
        const int cur = t & 1;
        if (t < qb) stage(cur ^ 1, t + 1); // issue next tile early (async)

        const bool diag = (t == qb);
        const int  cmax = diag ? (w + 1) : 4;

        // ---- S^T = K (Q*scale)^T ----
        f32x4 sc[4];
        __builtin_amdgcn_s_setprio(1);
        #pragma unroll
        for (int c = 0; c < 4; ++c) {
            if (c < cmax) {
                f32x4 acc = (f32x4){0.f, 0.f, 0.f, 0.f};
                #pragma unroll
                for (int dc = 0; dc < 2; ++dc) {
                    bf16x8 ak = *(const bf16x8*)&Klds[cur][swz(c * 16 + lo, dc * 32 + hi * 8)];
                    acc = __builtin_amdgcn_mfma_f32_16x16x32_bf16(ak, bq[dc], acc, 0, 0, 0);
                }
                sc[c] = acc;
            } else {
                sc[c] = (f32x4){-1e30f, -1e30f, -1e30f, -1e30f};
            }
        }
        __builtin_amdgcn_s_setprio(0);

        if (diag) {
            #pragma unroll
            for (int r = 0; r < 4; ++r)
                if (hi * 4 + r > lo) sc[w][r] = -1e30f;
        }

        // ---- online softmax: lane-local q-column; exp2 + defer-rescale ----
        float pm = -1e30f;
        #pragma unroll
        for (int c = 0; c < 4; ++c)
            pm = fmaxf(pm, fmaxf(fmaxf(sc[c][0], sc[c][1]), fmaxf(sc[c][2], sc[c][3])));
        pm = fmaxf(pm, __shfl_xor(pm, 16, 64));
        pm = fmaxf(pm, __shfl_xor(pm, 32, 64));

        if (!__all(pm - mrow <= 5.545f)) {   // T13: P bounded by e^5.545=256
            const float mn = fmaxf(mrow, pm);
            const float fr = exp2f((mrow - mn) * L2E);
            mrow = mn;
            lrow *= fr;
            #pragma unroll
            for (int n = 0; n < 4; ++n) oacc[n] *= fr;
        }

        const float mL = mrow * L2E;
        float rs = 0.f;
        #pragma unroll
        for (int c = 0; c < 4; ++c)
            #pragma unroll
            for (int r = 0; r < 4; ++r) {
                float p = exp2f(fmaf(sc[c][r], L2E, -mL));
                sc[c][r] = p;
                rs += p;
            }
        rs += __shfl_xor(rs, 16, 64);
        rs += __shfl_xor(rs, 32, 64);
        lrow += rs;

        // ---- pack P^T into PV B-fragments (pi-consistent with V image) ----
        bf16x8 pb[2];
        #pragma unroll
        for (int kc = 0; kc < 2; ++kc)
            #pragma unroll
            for (int j = 0; j < 8; ++j)
                pb[kc][j] = (__bf16)sc[kc * 2 + (j >> 2)][j & 3];

        // ---- O^T += V^T P^T ----
        __builtin_amdgcn_s_setprio(1);
        #pragma unroll
        for (int n = 0; n < 4; ++n) {
            bf16x8 av0 = *(const bf16x8*)&Vlds[cur][swz(n * 16 + lo, hi * 8)];
            oacc[n] = __builtin_amdgcn_mfma_f32_16x16x32_bf16(av0, pb[0], oacc[n], 0, 0, 0);
        }
        if (cmax > 2) {
            #pragma unroll
            for (int n = 0; n < 4; ++n) {
                bf16x8 av1 = *(const bf16x8*)&Vlds[cur][swz(n * 16 + lo, 32 + hi * 8)];
                oacc[n] = __builtin_amdgcn_mfma_f32_16x16x32_bf16(av1, pb[1], oacc[n], 0, 0, 0);
            }
        }
        __builtin_amdgcn_s_setprio(0);

        __syncthreads();   // drains vmcnt(0) (next tile landed) + barrier
    }

    // ---- epilogue ----
    const float linv = 1.0f / lrow;
    const int   q    = q0 + w * 16 + lo;
    #pragma unroll
    for (int n = 0; n < 4; ++n) {
        f32x4 o;
        #pragma unroll
        for (int r = 0; r < 4; ++r) o[r] = oacc[n][r] * linv;
        *(f32x4*)(Ob + (size_t)q * DH + n * 16 + hi * 4) = o;
    }
}

// ---------------------------------------------------------------------------
// Fallback (R2 kernel, proven 182us): used only if ws_size < 32MB.
// ---------------------------------------------------------------------------
__launch_bounds__(256, 4)
__global__ void attn_fwd(const float* __restrict__ Kg,
                         const float* __restrict__ Qg,
                         const float* __restrict__ Vg,
                         float* __restrict__ Og) {
    __shared__ __bf16 Klds[64 * 64];
    __shared__ __bf16 Vlds[64 * 64];

    const int qb  = blockIdx.x;
    const int bh  = blockIdx.y;
    const int tid = threadIdx.x;
    const int w   = tid >> 6;
    const int l   = tid & 63;
    const int lo  = l & 15;
    const int hi  = l >> 4;

    const int    q0   = qb * QB;
    const size_t base = (size_t)bh * S_LEN * DH;
    const float* Kb = Kg + base;
    const float* Qb = Qg + base;
    const float* Vb = Vg + base;
    float*       Ob = Og + base;

    bf16x8 bq[2];
    {
        const int qrow = q0 + w * 16 + lo;
        #pragma unroll
        for (int dc = 0; dc < 2; ++dc) {
            const float* p = Qb + (size_t)qrow * DH + dc * 32 + hi * 8;
            f32x4 v0 = *(const f32x4*)p;
            f32x4 v1 = *(const f32x4*)(p + 4);
            #pragma unroll
            for (int j = 0; j < 4; ++j) {
                bq[dc][j]     = (__bf16)(v0[j] * 0.125f);
                bq[dc][j + 4] = (__bf16)(v1[j] * 0.125f);
            }
        }
    }

    f32x4 oacc[4];
    #pragma unroll
    for (int n = 0; n < 4; ++n) oacc[n] = (f32x4){0.f, 0.f, 0.f, 0.f};
    float mrow = -1e30f, lrow = 0.f;

    const int krr = tid >> 4;
    const int kc4 = (tid & 15) * 4;

    for (int t = 0; t <= qb; ++t) {
        const int kv0 = t * KVB;
        {
            const float* kp = Kb + (size_t)kv0 * DH + kc4;
            #pragma unroll
            for (int i = 0; i < 4; ++i) {
                const int row = i * 16 + krr;
                f32x4 k4 = *(const f32x4*)(kp + (size_t)row * DH);
                bf16x4 kb;
                #pragma unroll
                for (int j = 0; j < 4; ++j) kb[j] = (__bf16)k4[j];
                *(bf16x4*)&Klds[swz(row, kc4)] = kb;
            }
        }
        {
            const float* vp = Vb + (size_t)kv0 * DH + l;
            float vv[16];
            #pragma unroll
            for (int i = 0; i < 16; ++i) {
                const int s  = w * 16 + i;
                const int kc = s >> 5, hs = (s >> 3) & 3, j = s & 7;
                const int kv = (kc * 2 + (j >> 2)) * 16 + hs * 4 + (j & 3);
                vv[i] = vp[(size_t)kv * DH];
            }
            bf16x8 v0, v1;
            #pragma unroll
            for (int i = 0; i < 8; ++i) { v0[i] = (__bf16)vv[i]; v1[i] = (__bf16)vv[8 + i]; }
            *(bf16x8*)&Vlds[swz(l, w * 16)]     = v0;
            *(bf16x8*)&Vlds[swz(l, w * 16 + 8)] = v1;
        }
        __syncthreads();

        const bool diag = (t == qb);
        const int  cmax = diag ? (w + 1) : 4;
        f32x4 sc[4];
        #pragma unroll
        for (int c = 0; c < 4; ++c) {
            if (c < cmax) {
                f32x4 acc = (f32x4){0.f, 0.f, 0.f, 0.f};
                #pragma unroll
                for (int dc = 0; dc < 2; ++dc) {
                    bf16x8 ak = *(const bf16x8*)&Klds[swz(c * 16 + lo, dc * 32 + hi * 8)];
                    acc = __builtin_amdgcn_mfma_f32_16x16x32_bf16(ak, bq[dc], acc, 0, 0, 0);
                }
                sc[c] = acc;
            } else {
                sc[c] = (f32x4){-1e30f, -1e30f, -1e30f, -1e30f};
            }
        }
        if (diag) {
            #pragma unroll
            for (int r = 0; r < 4; ++r)
                if (hi * 4 + r > lo) sc[w][r] = -1e30f;
        }

        float pm = -1e30f;
        #pragma unroll
        for (int c = 0; c < 4; ++c)
            #pragma unroll
            for (int r = 0; r < 4; ++r) pm = fmaxf(pm, sc[c][r]);
        pm = fmaxf(pm, __shfl_xor(pm, 16, 64));
        pm = fmaxf(pm, __shfl_xor(pm, 32, 64));

        const float mn = fmaxf(mrow, pm);
        const float fr = __expf(mrow - mn);
        mrow = mn;
        float rs = 0.f;
        #pragma unroll
        for (int c = 0; c < 4; ++c)
            #pragma unroll
            for (int r = 0; r < 4; ++r) {
                float p = __expf(sc[c][r] - mn);
                sc[c][r] = p;
                rs += p;
            }
        rs += __shfl_xor(rs, 16, 64);
        rs += __shfl_xor(rs, 32, 64);
        lrow = lrow * fr + rs;
        #pragma unroll
        for (int n = 0; n < 4; ++n) oacc[n] *= fr;

        bf16x8 pb[2];
        #pragma unroll
        for (int kc = 0; kc < 2; ++kc)
            #pragma unroll
            for (int j = 0; j < 8; ++j)
                pb[kc][j] = (__bf16)sc[kc * 2 + (j >> 2)][j & 3];

        #pragma unroll
        for (int n = 0; n < 4; ++n) {
            #pragma unroll
            for (int kc = 0; kc < 2; ++kc) {
                bf16x8 av = *(const bf16x8*)&Vlds[swz(n * 16 + lo, kc * 32 + hi * 8)];
                oacc[n] = __builtin_amdgcn_mfma_f32_16x16x32_bf16(av, pb[kc], oacc[n], 0, 0, 0);
            }
        }
        __syncthreads();
    }

    const float linv = 1.0f / lrow;
    const int   q    = q0 + w * 16 + lo;
    #pragma unroll
    for (int n = 0; n < 4; ++n) {
        f32x4 o;
        #pragma unroll
        for (int r = 0; r < 4; ++r) o[r] = oacc[n][r] * linv;
        *(f32x4*)(Ob + (size_t)q * DH + n * 16 + hi * 4) = o;
    }
}

extern "C" void kernel_launch(void* const* d_in, const int* in_sizes, int n_in,
                              void* d_out, int out_size, void* d_ws, size_t ws_size,
                              hipStream_t stream) {
    const float* keys    = (const float*)d_in[0];
    const float* queries = (const float*)d_in[1];
    const float* values  = (const float*)d_in[2];
    float* out = (float*)d_out;

    const int    BH   = in_sizes[0] / (S_LEN * DH);          // B*H = 64
    const size_t need = (size_t)BH * NT * TILE_BYTES;        // 32 MB

    if (ws_size >= need) {
        prep_kv<<<dim3(BH * NT), 256, 0, stream>>>(keys, values, (__bf16*)d_ws);
        attn_fwd2<<<dim3(S_LEN / QB, BH), 256, 0, stream>>>(queries, out,
                                                            (const __bf16*)d_ws);
    } else {
        attn_fwd<<<dim3(S_LEN / QB, BH), 256, 0, stream>>>(keys, queries, values, out);
    }
}

// Round 6
// 98.317 us; speedup vs baseline: 2.7279x; 1.5597x over previous
//
#include <hip/hip_runtime.h>
#include <hip/hip_bf16.h>

typedef __bf16 bf16x8 __attribute__((ext_vector_type(8)));
typedef __bf16 bf16x4 __attribute__((ext_vector_type(4)));
typedef float  f32x4  __attribute__((ext_vector_type(4)));

#define S_LEN 2048
#define DH    64
#define QB    64
#define KVB   64
#define NT    (S_LEN / KVB)     // 32 KV tiles
#define TILE_ELEMS 8192         // bf16 elems per (K+V) tile blob: 2 x 4096
#define TILE_BYTES 16384
#define L2E   1.44269504088896f

// Swizzled LDS element offset for a [rows][64] bf16 tile (128B row stride).
__device__ __forceinline__ int swz(int row, int col) {
    return (row << 6) + ((((col >> 3) ^ row) & 7) << 3) + (col & 7);
}

__device__ __forceinline__ void gl2lds16(const void* g, void* l) {
    __builtin_amdgcn_global_load_lds(
        (const __attribute__((address_space(1))) void*)g,
        (__attribute__((address_space(3))) void*)l, 16, 0, 0);
}

// ---------------------------------------------------------------------------
// Prep: fp32 K/V -> bf16 pre-swizzled LDS-image blobs (once per element).
// ---------------------------------------------------------------------------
__launch_bounds__(256, 4)
__global__ void prep_kv(const float* __restrict__ Kg,
                        const float* __restrict__ Vg,
                        __bf16* __restrict__ blob) {
    __shared__ __bf16 Vtmp[64 * 72];
    const int bt  = blockIdx.x;               // bh*32 + t
    const int tid = threadIdx.x;
    const size_t gbase = (size_t)bt * (KVB * DH);
    const float* Kt = Kg + gbase;
    const float* Vt = Vg + gbase;
    __bf16* outK = blob + (size_t)bt * TILE_ELEMS;
    __bf16* outV = outK + 4096;

    #pragma unroll
    for (int u = 0; u < 2; ++u) {
        const int m   = tid * 2 + u;
        const int row = m >> 3, cc = m & 7;
        const int c   = cc ^ (row & 7);
        const float* src = Kt + row * DH + c * 8;
        f32x4 a = *(const f32x4*)src;
        f32x4 b = *(const f32x4*)(src + 4);
        bf16x8 o;
        #pragma unroll
        for (int j = 0; j < 4; ++j) { o[j] = (__bf16)a[j]; o[j + 4] = (__bf16)b[j]; }
        *(bf16x8*)&outK[m * 8] = o;
    }
    {
        const int kv = tid >> 2, dq = (tid & 3) * 16;
        const float* src = Vt + kv * DH + dq;
        f32x4 v0 = *(const f32x4*)src,        v1 = *(const f32x4*)(src + 4);
        f32x4 v2 = *(const f32x4*)(src + 8),  v3 = *(const f32x4*)(src + 12);
        bf16x8 o0, o1;
        #pragma unroll
        for (int j = 0; j < 4; ++j) {
            o0[j] = (__bf16)v0[j]; o0[j + 4] = (__bf16)v1[j];
            o1[j] = (__bf16)v2[j]; o1[j + 4] = (__bf16)v3[j];
        }
        *(bf16x8*)&Vtmp[kv * 72 + dq]     = o0;
        *(bf16x8*)&Vtmp[kv * 72 + dq + 8] = o1;
    }
    __syncthreads();
    #pragma unroll
    for (int u = 0; u < 2; ++u) {
        const int m  = tid * 2 + u;
        const int d  = m >> 3, cc = m & 7;
        const int S8 = cc ^ (d & 7);
        const int kc = S8 >> 2, hs = S8 & 3;
        bf16x8 o;
        #pragma unroll
        for (int j = 0; j < 8; ++j) {
            const int kv = (kc * 2 + (j >> 2)) * 16 + hs * 4 + (j & 3);
            o[j] = Vtmp[kv * 72 + d];
        }
        *(bf16x8*)&outV[m * 8] = o;
    }
}

// ---------------------------------------------------------------------------
// Folded attention, simplified: block p handles Q-tiles {p, 31-p}.
// No MFMA skipping; only block-uniform branches (actA) and unconditional
// 16-element masks on diagonal tiles.  Per-part paths mirror the proven
// R4 kernel exactly.
// ---------------------------------------------------------------------------
__launch_bounds__(256, 4)
__global__ void attn_fold(const float* __restrict__ Qg,
                          float* __restrict__ Og,
                          const __bf16* __restrict__ blob) {
    __shared__ __bf16 Klds[2][4096];
    __shared__ __bf16 Vlds[2][4096];

    const int p   = blockIdx.x;        // 0..15
    const int bh  = blockIdx.y;
    const int qa  = p;                 // small Q-tile
    const int qbg = NT - 1 - p;        // large Q-tile (16..31)
    const int tid = threadIdx.x;
    const int w   = tid >> 6;
    const int l   = tid & 63;
    const int lo  = l & 15;
    const int hi  = l >> 4;

    const size_t base = (size_t)bh * S_LEN * DH;
    const float* Qb = Qg + base;
    float*       Ob = Og + base;
    const char*  blobB = (const char*)(blob + (size_t)bh * NT * TILE_ELEMS);

    // ---- Q fragments for both parts; scale 1/8 exact ----
    bf16x8 bqA[2], bqB[2];
    #pragma unroll
    for (int dc = 0; dc < 2; ++dc) {
        const float* pa = Qb + (size_t)(qa  * QB + w * 16 + lo) * DH + dc * 32 + hi * 8;
        const float* pb = Qb + (size_t)(qbg * QB + w * 16 + lo) * DH + dc * 32 + hi * 8;
        f32x4 a0 = *(const f32x4*)pa, a1 = *(const f32x4*)(pa + 4);
        f32x4 b0 = *(const f32x4*)pb, b1 = *(const f32x4*)(pb + 4);
        #pragma unroll
        for (int j = 0; j < 4; ++j) {
            bqA[dc][j]     = (__bf16)(a0[j] * 0.125f);
            bqA[dc][j + 4] = (__bf16)(a1[j] * 0.125f);
            bqB[dc][j]     = (__bf16)(b0[j] * 0.125f);
            bqB[dc][j + 4] = (__bf16)(b1[j] * 0.125f);
        }
    }

    f32x4 oaccA[4], oaccB[4];
    #pragma unroll
    for (int n = 0; n < 4; ++n) {
        oaccA[n] = (f32x4){0.f, 0.f, 0.f, 0.f};
        oaccB[n] = (f32x4){0.f, 0.f, 0.f, 0.f};
    }
    float mA = -1e30f, lA = 0.f, mB = -1e30f, lB = 0.f;

    auto stage = [&](int buf, int t) {
        const char* tb = blobB + (size_t)t * TILE_BYTES;
        char* kd = (char*)&Klds[buf][w * 1024];
        char* vd = (char*)&Vlds[buf][w * 1024];
        const char* ks = tb + w * 2048 + l * 16;
        const char* vs = tb + 8192 + w * 2048 + l * 16;
        gl2lds16(ks,        kd);
        gl2lds16(ks + 1024, kd + 1024);
        gl2lds16(vs,        vd);
        gl2lds16(vs + 1024, vd + 1024);
    };

    stage(0, 0);
    __syncthreads();

    for (int t = 0; t <= qbg; ++t) {
        const int cur = t & 1;
        if (t < qbg) stage(cur ^ 1, t + 1);

        const bool actA  = (t <= qa);     // block-uniform
        const bool diagA = (t == qa);
        const bool diagB = (t == qbg);

        // ---- S^T = K (Q*scale)^T, full 4 columns, shared ak reads ----
        f32x4 scA[4], scB[4];
        __builtin_amdgcn_s_setprio(1);
        #pragma unroll
        for (int c = 0; c < 4; ++c) {
            bf16x8 ak0 = *(const bf16x8*)&Klds[cur][swz(c * 16 + lo, hi * 8)];
            bf16x8 ak1 = *(const bf16x8*)&Klds[cur][swz(c * 16 + lo, 32 + hi * 8)];
            f32x4 ab = (f32x4){0.f, 0.f, 0.f, 0.f};
            ab = __builtin_amdgcn_mfma_f32_16x16x32_bf16(ak0, bqB[0], ab, 0, 0, 0);
            ab = __builtin_amdgcn_mfma_f32_16x16x32_bf16(ak1, bqB[1], ab, 0, 0, 0);
            scB[c] = ab;
            if (actA) {
                f32x4 aa = (f32x4){0.f, 0.f, 0.f, 0.f};
                aa = __builtin_amdgcn_mfma_f32_16x16x32_bf16(ak0, bqA[0], aa, 0, 0, 0);
                aa = __builtin_amdgcn_mfma_f32_16x16x32_bf16(ak1, bqA[1], aa, 0, 0, 0);
                scA[c] = aa;
            }
        }
        __builtin_amdgcn_s_setprio(0);

        // ---- diagonal masks: unconditional 16-element local compare ----
        const int qloc = w * 16 + lo;
        if (diagA) {
            #pragma unroll
            for (int c = 0; c < 4; ++c)
                #pragma unroll
                for (int r = 0; r < 4; ++r)
                    if (c * 16 + hi * 4 + r > qloc) scA[c][r] = -1e30f;
        }
        if (diagB) {
            #pragma unroll
            for (int c = 0; c < 4; ++c)
                #pragma unroll
                for (int r = 0; r < 4; ++r)
                    if (c * 16 + hi * 4 + r > qloc) scB[c][r] = -1e30f;
        }

        // ---- softmax + pack, part B (always) ----
        bf16x8 pbB[2];
        {
            float pm = -1e30f;
            #pragma unroll
            for (int c = 0; c < 4; ++c)
                pm = fmaxf(pm, fmaxf(fmaxf(scB[c][0], scB[c][1]),
                                     fmaxf(scB[c][2], scB[c][3])));
            pm = fmaxf(pm, __shfl_xor(pm, 16, 64));
            pm = fmaxf(pm, __shfl_xor(pm, 32, 64));
            if (!__all(pm - mB <= 5.545f)) {
                const float mn = fmaxf(mB, pm);
                const float fr = exp2f((mB - mn) * L2E);
                mB = mn; lB *= fr;
                #pragma unroll
                for (int n = 0; n < 4; ++n) oaccB[n] *= fr;
            }
            const float mL = mB * L2E;
            float rs = 0.f;
            #pragma unroll
            for (int c = 0; c < 4; ++c)
                #pragma unroll
                for (int r = 0; r < 4; ++r) {
                    float pe = exp2f(fmaf(scB[c][r], L2E, -mL));
                    scB[c][r] = pe;
                    rs += pe;
                }
            rs += __shfl_xor(rs, 16, 64);
            rs += __shfl_xor(rs, 32, 64);
            lB += rs;
            #pragma unroll
            for (int kc = 0; kc < 2; ++kc)
                #pragma unroll
                for (int j = 0; j < 8; ++j)
                    pbB[kc][j] = (__bf16)scB[kc * 2 + (j >> 2)][j & 3];
        }

        // ---- softmax + pack, part A (when active) ----
        bf16x8 pbA[2];
        if (actA) {
            float pm = -1e30f;
            #pragma unroll
            for (int c = 0; c < 4; ++c)
                pm = fmaxf(pm, fmaxf(fmaxf(scA[c][0], scA[c][1]),
                                     fmaxf(scA[c][2], scA[c][3])));
            pm = fmaxf(pm, __shfl_xor(pm, 16, 64));
            pm = fmaxf(pm, __shfl_xor(pm, 32, 64));
            if (!__all(pm - mA <= 5.545f)) {
                const float mn = fmaxf(mA, pm);
                const float fr = exp2f((mA - mn) * L2E);
                mA = mn; lA *= fr;
                #pragma unroll
                for (int n = 0; n < 4; ++n) oaccA[n] *= fr;
            }
            const float mL = mA * L2E;
            float rs = 0.f;
            #pragma unroll
            for (int c = 0; c < 4; ++c)
                #pragma unroll
                for (int r = 0; r < 4; ++r) {
                    float pe = exp2f(fmaf(scA[c][r], L2E, -mL));
                    scA[c][r] = pe;
                    rs += pe;
                }
            rs += __shfl_xor(rs, 16, 64);
            rs += __shfl_xor(rs, 32, 64);
            lA += rs;
            #pragma unroll
            for (int kc = 0; kc < 2; ++kc)
                #pragma unroll
                for (int j = 0; j < 8; ++j)
                    pbA[kc][j] = (__bf16)scA[kc * 2 + (j >> 2)][j & 3];
        }

        // ---- O^T += V^T P^T, full 8 MFMAs per part, shared av reads ----
        __builtin_amdgcn_s_setprio(1);
        #pragma unroll
        for (int n = 0; n < 4; ++n) {
            bf16x8 av0 = *(const bf16x8*)&Vlds[cur][swz(n * 16 + lo, hi * 8)];
            bf16x8 av1 = *(const bf16x8*)&Vlds[cur][swz(n * 16 + lo, 32 + hi * 8)];
            oaccB[n] = __builtin_amdgcn_mfma_f32_16x16x32_bf16(av0, pbB[0], oaccB[n], 0, 0, 0);
            oaccB[n] = __builtin_amdgcn_mfma_f32_16x16x32_bf16(av1, pbB[1], oaccB[n], 0, 0, 0);
            if (actA) {
                oaccA[n] = __builtin_amdgcn_mfma_f32_16x16x32_bf16(av0, pbA[0], oaccA[n], 0, 0, 0);
                oaccA[n] = __builtin_amdgcn_mfma_f32_16x16x32_bf16(av1, pbA[1], oaccA[n], 0, 0, 0);
            }
        }
        __builtin_amdgcn_s_setprio(0);

        __syncthreads();   // drains vmcnt (next tile landed) + barrier
    }

    // ---- epilogue: both parts ----
    {
        const float linv = 1.0f / lA;
        const int   q    = qa * QB + w * 16 + lo;
        #pragma unroll
        for (int n = 0; n < 4; ++n) {
            f32x4 o;
            #pragma unroll
            for (int r = 0; r < 4; ++r) o[r] = oaccA[n][r] * linv;
            *(f32x4*)(Ob + (size_t)q * DH + n * 16 + hi * 4) = o;
        }
    }
    {
        const float linv = 1.0f / lB;
        const int   q    = qbg * QB + w * 16 + lo;
        #pragma unroll
        for (int n = 0; n < 4; ++n) {
            f32x4 o;
            #pragma unroll
            for (int r = 0; r < 4; ++r) o[r] = oaccB[n][r] * linv;
            *(f32x4*)(Ob + (size_t)q * DH + n * 16 + hi * 4) = o;
        }
    }
}

// ---------------------------------------------------------------------------
// Fallback (R2 kernel): used only if ws_size < 32MB.
// ---------------------------------------------------------------------------
__launch_bounds__(256, 4)
__global__ void attn_fwd(const float* __restrict__ Kg,
                         const float* __restrict__ Qg,
                         const float* __restrict__ Vg,
                         float* __restrict__ Og) {
    __shared__ __bf16 Klds[64 * 64];
    __shared__ __bf16 Vlds[64 * 64];

    const int qb  = blockIdx.x;
    const int bh  = blockIdx.y;
    const int tid = threadIdx.x;
    const int w   = tid >> 6;
    const int l   = tid & 63;
    const int lo  = l & 15;
    const int hi  = l >> 4;

    const int    q0   = qb * QB;
    const size_t base = (size_t)bh * S_LEN * DH;
    const float* Kb = Kg + base;
    const float* Qb = Qg + base;
    const float* Vb = Vg + base;
    float*       Ob = Og + base;

    bf16x8 bq[2];
    {
        const int qrow = q0 + w * 16 + lo;
        #pragma unroll
        for (int dc = 0; dc < 2; ++dc) {
            const float* p = Qb + (size_t)qrow * DH + dc * 32 + hi * 8;
            f32x4 v0 = *(const f32x4*)p;
            f32x4 v1 = *(const f32x4*)(p + 4);
            #pragma unroll
            for (int j = 0; j < 4; ++j) {
                bq[dc][j]     = (__bf16)(v0[j] * 0.125f);
                bq[dc][j + 4] = (__bf16)(v1[j] * 0.125f);
            }
        }
    }

    f32x4 oacc[4];
    #pragma unroll
    for (int n = 0; n < 4; ++n) oacc[n] = (f32x4){0.f, 0.f, 0.f, 0.f};
    float mrow = -1e30f, lrow = 0.f;

    const int krr = tid >> 4;
    const int kc4 = (tid & 15) * 4;

    for (int t = 0; t <= qb; ++t) {
        const int kv0 = t * KVB;
        {
            const float* kp = Kb + (size_t)kv0 * DH + kc4;
            #pragma unroll
            for (int i = 0; i < 4; ++i) {
                const int row = i * 16 + krr;
                f32x4 k4 = *(const f32x4*)(kp + (size_t)row * DH);
                bf16x4 kb;
                #pragma unroll
                for (int j = 0; j < 4; ++j) kb[j] = (__bf16)k4[j];
                *(bf16x4*)&Klds[swz(row, kc4)] = kb;
            }
        }
        {
            const float* vp = Vb + (size_t)kv0 * DH + l;
            float vv[16];
            #pragma unroll
            for (int i = 0; i < 16; ++i) {
                const int s  = w * 16 + i;
                const int kc = s >> 5, hs = (s >> 3) & 3, j = s & 7;
                const int kv = (kc * 2 + (j >> 2)) * 16 + hs * 4 + (j & 3);
                vv[i] = vp[(size_t)kv * DH];
            }
            bf16x8 v0, v1;
            #pragma unroll
            for (int i = 0; i < 8; ++i) { v0[i] = (__bf16)vv[i]; v1[i] = (__bf16)vv[8 + i]; }
            *(bf16x8*)&Vlds[swz(l, w * 16)]     = v0;
            *(bf16x8*)&Vlds[swz(l, w * 16 + 8)] = v1;
        }
        __syncthreads();

        const bool diag = (t == qb);
        const int  cmax = diag ? (w + 1) : 4;
        f32x4 sc[4];
        #pragma unroll
        for (int c = 0; c < 4; ++c) {
            if (c < cmax) {
                f32x4 acc = (f32x4){0.f, 0.f, 0.f, 0.f};
                #pragma unroll
                for (int dc = 0; dc < 2; ++dc) {
                    bf16x8 ak = *(const bf16x8*)&Klds[swz(c * 16 + lo, dc * 32 + hi * 8)];
                    acc = __builtin_amdgcn_mfma_f32_16x16x32_bf16(ak, bq[dc], acc, 0, 0, 0);
                }
                sc[c] = acc;
            } else {
                sc[c] = (f32x4){-1e30f, -1e30f, -1e30f, -1e30f};
            }
        }
        if (diag) {
            #pragma unroll
            for (int r = 0; r < 4; ++r)
                if (hi * 4 + r > lo) sc[w][r] = -1e30f;
        }

        float pm = -1e30f;
        #pragma unroll
        for (int c = 0; c < 4; ++c)
            #pragma unroll
            for (int r = 0; r < 4; ++r) pm = fmaxf(pm, sc[c][r]);
        pm = fmaxf(pm, __shfl_xor(pm, 16, 64));
        pm = fmaxf(pm, __shfl_xor(pm, 32, 64));

        const float mn = fmaxf(mrow, pm);
        const float fr = __expf(mrow - mn);
        mrow = mn;
        float rs = 0.f;
        #pragma unroll
        for (int c = 0; c < 4; ++c)
            #pragma unroll
            for (int r = 0; r < 4; ++r) {
                float pe = __expf(sc[c][r] - mn);
                sc[c][r] = pe;
                rs += pe;
            }
        rs += __shfl_xor(rs, 16, 64);
        rs += __shfl_xor(rs, 32, 64);
        lrow = lrow * fr + rs;
        #pragma unroll
        for (int n = 0; n < 4; ++n) oacc[n] *= fr;

        bf16x8 pb[2];
        #pragma unroll
        for (int kc = 0; kc < 2; ++kc)
            #pragma unroll
            for (int j = 0; j < 8; ++j)
                pb[kc][j] = (__bf16)sc[kc * 2 + (j >> 2)][j & 3];

        #pragma unroll
        for (int n = 0; n < 4; ++n) {
            #pragma unroll
            for (int kc = 0; kc < 2; ++kc) {
                bf16x8 av = *(const bf16x8*)&Vlds[swz(n * 16 + lo, kc * 32 + hi * 8)];
                oacc[n] = __builtin_amdgcn_mfma_f32_16x16x32_bf16(av, pb[kc], oacc[n], 0, 0, 0);
            }
        }
        __syncthreads();
    }

    const float linv = 1.0f / lrow;
    const int   q    = q0 + w * 16 + lo;
    #pragma unroll
    for (int n = 0; n < 4; ++n) {
        f32x4 o;
        #pragma unroll
        for (int r = 0; r < 4; ++r) o[r] = oacc[n][r] * linv;
        *(f32x4*)(Ob + (size_t)q * DH + n * 16 + hi * 4) = o;
    }
}

extern "C" void kernel_launch(void* const* d_in, const int* in_sizes, int n_in,
                              void* d_out, int out_size, void* d_ws, size_t ws_size,
                              hipStream_t stream) {
    const float* keys    = (const float*)d_in[0];
    const float* queries = (const float*)d_in[1];
    const float* values  = (const float*)d_in[2];
    float* out = (float*)d_out;

    const int    BH   = in_sizes[0] / (S_LEN * DH);          // B*H = 64
    const size_t need = (size_t)BH * NT * TILE_BYTES;        // 32 MB

    if (ws_size >= need) {
        prep_kv<<<dim3(BH * NT), 256, 0, stream>>>(keys, values, (__bf16*)d_ws);
        attn_fold<<<dim3(NT / 2, BH), 256, 0, stream>>>(queries, out,
                                                        (const __bf16*)d_ws);
    } else {
        attn_fwd<<<dim3(S_LEN / QB, BH), 256, 0, stream>>>(keys, queries, values, out);
    }
}

// Round 7
// 88.038 us; speedup vs baseline: 3.0464x; 1.1167x over previous
//
#include <hip/hip_runtime.h>
#include <hip/hip_bf16.h>

typedef __bf16 bf16x8 __attribute__((ext_vector_type(8)));
typedef __bf16 bf16x4 __attribute__((ext_vector_type(4)));
typedef float  f32x4  __attribute__((ext_vector_type(4)));

#define S_LEN 2048
#define DH    64
#define QB    64
#define KVB   64
#define NT    (S_LEN / KVB)     // 32 KV tiles
#define TILE_ELEMS 8192         // bf16 elems per (K+V) tile blob: 2 x 4096
#define TILE_BYTES 16384
#define L2E   1.44269504088896f

// Swizzled LDS element offset for a [rows][64] bf16 tile (128B row stride).
__device__ __forceinline__ int swz(int row, int col) {
    return (row << 6) + ((((col >> 3) ^ row) & 7) << 3) + (col & 7);
}

__device__ __forceinline__ void gl2lds16(const void* g, void* l) {
    __builtin_amdgcn_global_load_lds(
        (const __attribute__((address_space(1))) void*)g,
        (__attribute__((address_space(3))) void*)l, 16, 0, 0);
}

// bare v_exp_f32: args are <= 0 after max-subtraction; underflow->0 is wanted
__device__ __forceinline__ float fexp2(float x) {
    return __builtin_amdgcn_exp2f(x);
}

// ---------------------------------------------------------------------------
// Prep: fp32 K/V -> bf16 pre-swizzled LDS-image blobs (once per element).
// ---------------------------------------------------------------------------
__launch_bounds__(256, 4)
__global__ void prep_kv(const float* __restrict__ Kg,
                        const float* __restrict__ Vg,
                        __bf16* __restrict__ blob) {
    __shared__ __bf16 Vtmp[64 * 72];
    const int bt  = blockIdx.x;               // bh*32 + t
    const int tid = threadIdx.x;
    const size_t gbase = (size_t)bt * (KVB * DH);
    const float* Kt = Kg + gbase;
    const float* Vt = Vg + gbase;
    __bf16* outK = blob + (size_t)bt * TILE_ELEMS;
    __bf16* outV = outK + 4096;

    #pragma unroll
    for (int u = 0; u < 2; ++u) {
        const int m   = tid * 2 + u;
        const int row = m >> 3, cc = m & 7;
        const int c   = cc ^ (row & 7);
        const float* src = Kt + row * DH + c * 8;
        f32x4 a = *(const f32x4*)src;
        f32x4 b = *(const f32x4*)(src + 4);
        bf16x8 o;
        #pragma unroll
        for (int j = 0; j < 4; ++j) { o[j] = (__bf16)a[j]; o[j + 4] = (__bf16)b[j]; }
        *(bf16x8*)&outK[m * 8] = o;
    }
    {
        const int kv = tid >> 2, dq = (tid & 3) * 16;
        const float* src = Vt + kv * DH + dq;
        f32x4 v0 = *(const f32x4*)src,        v1 = *(const f32x4*)(src + 4);
        f32x4 v2 = *(const f32x4*)(src + 8),  v3 = *(const f32x4*)(src + 12);
        bf16x8 o0, o1;
        #pragma unroll
        for (int j = 0; j < 4; ++j) {
            o0[j] = (__bf16)v0[j]; o0[j + 4] = (__bf16)v1[j];
            o1[j] = (__bf16)v2[j]; o1[j + 4] = (__bf16)v3[j];
        }
        *(bf16x8*)&Vtmp[kv * 72 + dq]     = o0;
        *(bf16x8*)&Vtmp[kv * 72 + dq + 8] = o1;
    }
    __syncthreads();
    #pragma unroll
    for (int u = 0; u < 2; ++u) {
        const int m  = tid * 2 + u;
        const int d  = m >> 3, cc = m & 7;
        const int S8 = cc ^ (d & 7);
        const int kc = S8 >> 2, hs = S8 & 3;
        bf16x8 o;
        #pragma unroll
        for (int j = 0; j < 8; ++j) {
            const int kv = (kc * 2 + (j >> 2)) * 16 + hs * 4 + (j & 3);
            o[j] = Vtmp[kv * 72 + d];
        }
        *(bf16x8*)&outV[m * 8] = o;
    }
}

// ---------------------------------------------------------------------------
// Folded attention: block p handles Q-tiles {p, 31-p}.  R6 structure, with
// native exp2 + hoisted LDS offsets.
// ---------------------------------------------------------------------------
__launch_bounds__(256, 4)
__global__ void attn_fold(const float* __restrict__ Qg,
                          float* __restrict__ Og,
                          const __bf16* __restrict__ blob) {
    __shared__ __bf16 Klds[2][4096];
    __shared__ __bf16 Vlds[2][4096];

    const int p   = blockIdx.x;        // 0..15
    const int bh  = blockIdx.y;
    const int qa  = p;                 // small Q-tile
    const int qbg = NT - 1 - p;        // large Q-tile (16..31)
    const int tid = threadIdx.x;
    const int w   = tid >> 6;
    const int l   = tid & 63;
    const int lo  = l & 15;
    const int hi  = l >> 4;

    const size_t base = (size_t)bh * S_LEN * DH;
    const float* Qb = Qg + base;
    float*       Ob = Og + base;
    const char*  blobB = (const char*)(blob + (size_t)bh * NT * TILE_ELEMS);

    // ---- hoisted swizzled LDS element offsets (loop-invariant) ----
    int koff[4][2], voff[4][2];
    #pragma unroll
    for (int c = 0; c < 4; ++c) {
        koff[c][0] = swz(c * 16 + lo, hi * 8);
        koff[c][1] = swz(c * 16 + lo, 32 + hi * 8);
        voff[c][0] = koff[c][0];           // same formula for V tile
        voff[c][1] = koff[c][1];
    }

    // ---- Q fragments for both parts; scale 1/8 exact ----
    bf16x8 bqA[2], bqB[2];
    #pragma unroll
    for (int dc = 0; dc < 2; ++dc) {
        const float* pa = Qb + (size_t)(qa  * QB + w * 16 + lo) * DH + dc * 32 + hi * 8;
        const float* pb = Qb + (size_t)(qbg * QB + w * 16 + lo) * DH + dc * 32 + hi * 8;
        f32x4 a0 = *(const f32x4*)pa, a1 = *(const f32x4*)(pa + 4);
        f32x4 b0 = *(const f32x4*)pb, b1 = *(const f32x4*)(pb + 4);
        #pragma unroll
        for (int j = 0; j < 4; ++j) {
            bqA[dc][j]     = (__bf16)(a0[j] * 0.125f);
            bqA[dc][j + 4] = (__bf16)(a1[j] * 0.125f);
            bqB[dc][j]     = (__bf16)(b0[j] * 0.125f);
            bqB[dc][j + 4] = (__bf16)(b1[j] * 0.125f);
        }
    }

    f32x4 oaccA[4], oaccB[4];
    #pragma unroll
    for (int n = 0; n < 4; ++n) {
        oaccA[n] = (f32x4){0.f, 0.f, 0.f, 0.f};
        oaccB[n] = (f32x4){0.f, 0.f, 0.f, 0.f};
    }
    float mA = -1e30f, lA = 0.f, mB = -1e30f, lB = 0.f;

    auto stage = [&](int buf, int t) {
        const char* tb = blobB + (size_t)t * TILE_BYTES;
        char* kd = (char*)&Klds[buf][w * 1024];
        char* vd = (char*)&Vlds[buf][w * 1024];
        const char* ks = tb + w * 2048 + l * 16;
        const char* vs = tb + 8192 + w * 2048 + l * 16;
        gl2lds16(ks,        kd);
        gl2lds16(ks + 1024, kd + 1024);
        gl2lds16(vs,        vd);
        gl2lds16(vs + 1024, vd + 1024);
    };

    stage(0, 0);
    __syncthreads();

    for (int t = 0; t <= qbg; ++t) {
        const int cur = t & 1;
        if (t < qbg) stage(cur ^ 1, t + 1);

        const bool actA  = (t <= qa);     // block-uniform
        const bool diagA = (t == qa);
        const bool diagB = (t == qbg);
        const __bf16* Kc = &Klds[cur][0];
        const __bf16* Vc = &Vlds[cur][0];

        // ---- S^T = K (Q*scale)^T, full 4 columns, shared ak reads ----
        f32x4 scA[4], scB[4];
        __builtin_amdgcn_s_setprio(1);
        #pragma unroll
        for (int c = 0; c < 4; ++c) {
            bf16x8 ak0 = *(const bf16x8*)&Kc[koff[c][0]];
            bf16x8 ak1 = *(const bf16x8*)&Kc[koff[c][1]];
            f32x4 ab = (f32x4){0.f, 0.f, 0.f, 0.f};
            ab = __builtin_amdgcn_mfma_f32_16x16x32_bf16(ak0, bqB[0], ab, 0, 0, 0);
            ab = __builtin_amdgcn_mfma_f32_16x16x32_bf16(ak1, bqB[1], ab, 0, 0, 0);
            scB[c] = ab;
            if (actA) {
                f32x4 aa = (f32x4){0.f, 0.f, 0.f, 0.f};
                aa = __builtin_amdgcn_mfma_f32_16x16x32_bf16(ak0, bqA[0], aa, 0, 0, 0);
                aa = __builtin_amdgcn_mfma_f32_16x16x32_bf16(ak1, bqA[1], aa, 0, 0, 0);
                scA[c] = aa;
            }
        }
        __builtin_amdgcn_s_setprio(0);

        // ---- diagonal masks: unconditional 16-element local compare ----
        const int qloc = w * 16 + lo;
        if (diagA) {
            #pragma unroll
            for (int c = 0; c < 4; ++c)
                #pragma unroll
                for (int r = 0; r < 4; ++r)
                    if (c * 16 + hi * 4 + r > qloc) scA[c][r] = -1e30f;
        }
        if (diagB) {
            #pragma unroll
            for (int c = 0; c < 4; ++c)
                #pragma unroll
                for (int r = 0; r < 4; ++r)
                    if (c * 16 + hi * 4 + r > qloc) scB[c][r] = -1e30f;
        }

        // ---- softmax + pack, part B (always) ----
        bf16x8 pbB[2];
        {
            float pm = -1e30f;
            #pragma unroll
            for (int c = 0; c < 4; ++c)
                pm = fmaxf(pm, fmaxf(fmaxf(scB[c][0], scB[c][1]),
                                     fmaxf(scB[c][2], scB[c][3])));
            pm = fmaxf(pm, __shfl_xor(pm, 16, 64));
            pm = fmaxf(pm, __shfl_xor(pm, 32, 64));
            if (!__all(pm - mB <= 5.545f)) {
                const float mn = fmaxf(mB, pm);
                const float fr = fexp2((mB - mn) * L2E);
                mB = mn; lB *= fr;
                #pragma unroll
                for (int n = 0; n < 4; ++n) oaccB[n] *= fr;
            }
            const float mL = mB * L2E;
            float rs = 0.f;
            #pragma unroll
            for (int c = 0; c < 4; ++c)
                #pragma unroll
                for (int r = 0; r < 4; ++r) {
                    float pe = fexp2(fmaf(scB[c][r], L2E, -mL));
                    scB[c][r] = pe;
                    rs += pe;
                }
            rs += __shfl_xor(rs, 16, 64);
            rs += __shfl_xor(rs, 32, 64);
            lB += rs;
            #pragma unroll
            for (int kc = 0; kc < 2; ++kc)
                #pragma unroll
                for (int j = 0; j < 8; ++j)
                    pbB[kc][j] = (__bf16)scB[kc * 2 + (j >> 2)][j & 3];
        }

        // ---- softmax + pack, part A (when active) ----
        bf16x8 pbA[2];
        if (actA) {
            float pm = -1e30f;
            #pragma unroll
            for (int c = 0; c < 4; ++c)
                pm = fmaxf(pm, fmaxf(fmaxf(scA[c][0], scA[c][1]),
                                     fmaxf(scA[c][2], scA[c][3])));
            pm = fmaxf(pm, __shfl_xor(pm, 16, 64));
            pm = fmaxf(pm, __shfl_xor(pm, 32, 64));
            if (!__all(pm - mA <= 5.545f)) {
                const float mn = fmaxf(mA, pm);
                const float fr = fexp2((mA - mn) * L2E);
                mA = mn; lA *= fr;
                #pragma unroll
                for (int n = 0; n < 4; ++n) oaccA[n] *= fr;
            }
            const float mL = mA * L2E;
            float rs = 0.f;
            #pragma unroll
            for (int c = 0; c < 4; ++c)
                #pragma unroll
                for (int r = 0; r < 4; ++r) {
                    float pe = fexp2(fmaf(scA[c][r], L2E, -mL));
                    scA[c][r] = pe;
                    rs += pe;
                }
            rs += __shfl_xor(rs, 16, 64);
            rs += __shfl_xor(rs, 32, 64);
            lA += rs;
            #pragma unroll
            for (int kc = 0; kc < 2; ++kc)
                #pragma unroll
                for (int j = 0; j < 8; ++j)
                    pbA[kc][j] = (__bf16)scA[kc * 2 + (j >> 2)][j & 3];
        }

        // ---- O^T += V^T P^T, full 8 MFMAs per part, shared av reads ----
        __builtin_amdgcn_s_setprio(1);
        #pragma unroll
        for (int n = 0; n < 4; ++n) {
            bf16x8 av0 = *(const bf16x8*)&Vc[voff[n][0]];
            bf16x8 av1 = *(const bf16x8*)&Vc[voff[n][1]];
            oaccB[n] = __builtin_amdgcn_mfma_f32_16x16x32_bf16(av0, pbB[0], oaccB[n], 0, 0, 0);
            oaccB[n] = __builtin_amdgcn_mfma_f32_16x16x32_bf16(av1, pbB[1], oaccB[n], 0, 0, 0);
            if (actA) {
                oaccA[n] = __builtin_amdgcn_mfma_f32_16x16x32_bf16(av0, pbA[0], oaccA[n], 0, 0, 0);
                oaccA[n] = __builtin_amdgcn_mfma_f32_16x16x32_bf16(av1, pbA[1], oaccA[n], 0, 0, 0);
            }
        }
        __builtin_amdgcn_s_setprio(0);

        __syncthreads();   // drains vmcnt (next tile landed) + barrier
    }

    // ---- epilogue: both parts ----
    {
        const float linv = 1.0f / lA;
        const int   q    = qa * QB + w * 16 + lo;
        #pragma unroll
        for (int n = 0; n < 4; ++n) {
            f32x4 o;
            #pragma unroll
            for (int r = 0; r < 4; ++r) o[r] = oaccA[n][r] * linv;
            *(f32x4*)(Ob + (size_t)q * DH + n * 16 + hi * 4) = o;
        }
    }
    {
        const float linv = 1.0f / lB;
        const int   q    = qbg * QB + w * 16 + lo;
        #pragma unroll
        for (int n = 0; n < 4; ++n) {
            f32x4 o;
            #pragma unroll
            for (int r = 0; r < 4; ++r) o[r] = oaccB[n][r] * linv;
            *(f32x4*)(Ob + (size_t)q * DH + n * 16 + hi * 4) = o;
        }
    }
}

// ---------------------------------------------------------------------------
// Fallback (R2 kernel): used only if ws_size < 32MB.
// ---------------------------------------------------------------------------
__launch_bounds__(256, 4)
__global__ void attn_fwd(const float* __restrict__ Kg,
                         const float* __restrict__ Qg,
                         const float* __restrict__ Vg,
                         float* __restrict__ Og) {
    __shared__ __bf16 Klds[64 * 64];
    __shared__ __bf16 Vlds[64 * 64];

    const int qb  = blockIdx.x;
    const int bh  = blockIdx.y;
    const int tid = threadIdx.x;
    const int w   = tid >> 6;
    const int l   = tid & 63;
    const int lo  = l & 15;
    const int hi  = l >> 4;

    const int    q0   = qb * QB;
    const size_t base = (size_t)bh * S_LEN * DH;
    const float* Kb = Kg + base;
    const float* Qb = Qg + base;
    const float* Vb = Vg + base;
    float*       Ob = Og + base;

    bf16x8 bq[2];
    {
        const int qrow = q0 + w * 16 + lo;
        #pragma unroll
        for (int dc = 0; dc < 2; ++dc) {
            const float* p = Qb + (size_t)qrow * DH + dc * 32 + hi * 8;
            f32x4 v0 = *(const f32x4*)p;
            f32x4 v1 = *(const f32x4*)(p + 4);
            #pragma unroll
            for (int j = 0; j < 4; ++j) {
                bq[dc][j]     = (__bf16)(v0[j] * 0.125f);
                bq[dc][j + 4] = (__bf16)(v1[j] * 0.125f);
            }
        }
    }

    f32x4 oacc[4];
    #pragma unroll
    for (int n = 0; n < 4; ++n) oacc[n] = (f32x4){0.f, 0.f, 0.f, 0.f};
    float mrow = -1e30f, lrow = 0.f;

    const int krr = tid >> 4;
    const int kc4 = (tid & 15) * 4;

    for (int t = 0; t <= qb; ++t) {
        const int kv0 = t * KVB;
        {
            const float* kp = Kb + (size_t)kv0 * DH + kc4;
            #pragma unroll
            for (int i = 0; i < 4; ++i) {
                const int row = i * 16 + krr;
                f32x4 k4 = *(const f32x4*)(kp + (size_t)row * DH);
                bf16x4 kb;
                #pragma unroll
                for (int j = 0; j < 4; ++j) kb[j] = (__bf16)k4[j];
                *(bf16x4*)&Klds[swz(row, kc4)] = kb;
            }
        }
        {
            const float* vp = Vb + (size_t)kv0 * DH + l;
            float vv[16];
            #pragma unroll
            for (int i = 0; i < 16; ++i) {
                const int s  = w * 16 + i;
                const int kc = s >> 5, hs = (s >> 3) & 3, j = s & 7;
                const int kv = (kc * 2 + (j >> 2)) * 16 + hs * 4 + (j & 3);
                vv[i] = vp[(size_t)kv * DH];
            }
            bf16x8 v0, v1;
            #pragma unroll
            for (int i = 0; i < 8; ++i) { v0[i] = (__bf16)vv[i]; v1[i] = (__bf16)vv[8 + i]; }
            *(bf16x8*)&Vlds[swz(l, w * 16)]     = v0;
            *(bf16x8*)&Vlds[swz(l, w * 16 + 8)] = v1;
        }
        __syncthreads();

        const bool diag = (t == qb);
        const int  cmax = diag ? (w + 1) : 4;
        f32x4 sc[4];
        #pragma unroll
        for (int c = 0; c < 4; ++c) {
            if (c < cmax) {
                f32x4 acc = (f32x4){0.f, 0.f, 0.f, 0.f};
                #pragma unroll
                for (int dc = 0; dc < 2; ++dc) {
                    bf16x8 ak = *(const bf16x8*)&Klds[swz(c * 16 + lo, dc * 32 + hi * 8)];
                    acc = __builtin_amdgcn_mfma_f32_16x16x32_bf16(ak, bq[dc], acc, 0, 0, 0);
                }
                sc[c] = acc;
            } else {
                sc[c] = (f32x4){-1e30f, -1e30f, -1e30f, -1e30f};
            }
        }
        if (diag) {
            #pragma unroll
            for (int r = 0; r < 4; ++r)
                if (hi * 4 + r > lo) sc[w][r] = -1e30f;
        }

        float pm = -1e30f;
        #pragma unroll
        for (int c = 0; c < 4; ++c)
            #pragma unroll
            for (int r = 0; r < 4; ++r) pm = fmaxf(pm, sc[c][r]);
        pm = fmaxf(pm, __shfl_xor(pm, 16, 64));
        pm = fmaxf(pm, __shfl_xor(pm, 32, 64));

        const float mn = fmaxf(mrow, pm);
        const float fr = __expf(mrow - mn);
        mrow = mn;
        float rs = 0.f;
        #pragma unroll
        for (int c = 0; c < 4; ++c)
            #pragma unroll
            for (int r = 0; r < 4; ++r) {
                float pe = __expf(sc[c][r] - mn);
                sc[c][r] = pe;
                rs += pe;
            }
        rs += __shfl_xor(rs, 16, 64);
        rs += __shfl_xor(rs, 32, 64);
        lrow = lrow * fr + rs;
        #pragma unroll
        for (int n = 0; n < 4; ++n) oacc[n] *= fr;

        bf16x8 pb[2];
        #pragma unroll
        for (int kc = 0; kc < 2; ++kc)
            #pragma unroll
            for (int j = 0; j < 8; ++j)
                pb[kc][j] = (__bf16)sc[kc * 2 + (j >> 2)][j & 3];

        #pragma unroll
        for (int n = 0; n < 4; ++n) {
            #pragma unroll
            for (int kc = 0; kc < 2; ++kc) {
                bf16x8 av = *(const bf16x8*)&Vlds[swz(n * 16 + lo, kc * 32 + hi * 8)];
                oacc[n] = __builtin_amdgcn_mfma_f32_16x16x32_bf16(av, pb[kc], oacc[n], 0, 0, 0);
            }
        }
        __syncthreads();
    }

    const float linv = 1.0f / lrow;
    const int   q    = q0 + w * 16 + lo;
    #pragma unroll
    for (int n = 0; n < 4; ++n) {
        f32x4 o;
        #pragma unroll
        for (int r = 0; r < 4; ++r) o[r] = oacc[n][r] * linv;
        *(f32x4*)(Ob + (size_t)q * DH + n * 16 + hi * 4) = o;
    }
}

extern "C" void kernel_launch(void* const* d_in, const int* in_sizes, int n_in,
                              void* d_out, int out_size, void* d_ws, size_t ws_size,
                              hipStream_t stream) {
    const float* keys    = (const float*)d_in[0];
    const float* queries = (const float*)d_in[1];
    const float* values  = (const float*)d_in[2];
    float* out = (float*)d_out;

    const int    BH   = in_sizes[0] / (S_LEN * DH);          // B*H = 64
    const size_t need = (size_t)BH * NT * TILE_BYTES;        // 32 MB

    if (ws_size >= need) {
        prep_kv<<<dim3(BH * NT), 256, 0, stream>>>(keys, values, (__bf16*)d_ws);
        attn_fold<<<dim3(NT / 2, BH), 256, 0, stream>>>(queries, out,
                                                        (const __bf16*)d_ws);
    } else {
        attn_fwd<<<dim3(S_LEN / QB, BH), 256, 0, stream>>>(keys, queries, values, out);
    }
}

// Round 8
// 83.341 us; speedup vs baseline: 3.2181x; 1.0564x over previous
//
#include <hip/hip_runtime.h>
#include <hip/hip_bf16.h>

typedef __bf16 bf16x8 __attribute__((ext_vector_type(8)));
typedef __bf16 bf16x4 __attribute__((ext_vector_type(4)));
typedef float  f32x4  __attribute__((ext_vector_type(4)));

#define S_LEN 2048
#define DH    64
#define QB    64
#define KVB   64
#define NT    (S_LEN / KVB)     // 32 KV tiles
#define TILE_ELEMS 8192         // bf16 elems per (K+V) tile blob: 2 x 4096
#define TILE_BYTES 16384
#define L2E   1.44269504088896f

// Swizzled LDS element offset for a [rows][64] bf16 tile (128B row stride).
__device__ __forceinline__ int swz(int row, int col) {
    return (row << 6) + ((((col >> 3) ^ row) & 7) << 3) + (col & 7);
}

__device__ __forceinline__ void gl2lds16(const void* g, void* l) {
    __builtin_amdgcn_global_load_lds(
        (const __attribute__((address_space(1))) void*)g,
        (__attribute__((address_space(3))) void*)l, 16, 0, 0);
}

// bare v_exp_f32: args are <= 0 after max-subtraction; underflow->0 is wanted
__device__ __forceinline__ float fexp2(float x) {
    return __builtin_amdgcn_exp2f(x);
}

// ---------------------------------------------------------------------------
// Prep: fp32 K/V -> bf16 pre-swizzled LDS-image blobs (once per element).
// ---------------------------------------------------------------------------
__launch_bounds__(256, 4)
__global__ void prep_kv(const float* __restrict__ Kg,
                        const float* __restrict__ Vg,
                        __bf16* __restrict__ blob) {
    __shared__ __bf16 Vtmp[64 * 72];
    const int bt  = blockIdx.x;               // bh*32 + t
    const int tid = threadIdx.x;
    const size_t gbase = (size_t)bt * (KVB * DH);
    const float* Kt = Kg + gbase;
    const float* Vt = Vg + gbase;
    __bf16* outK = blob + (size_t)bt * TILE_ELEMS;
    __bf16* outV = outK + 4096;

    #pragma unroll
    for (int u = 0; u < 2; ++u) {
        const int m   = tid * 2 + u;
        const int row = m >> 3, cc = m & 7;
        const int c   = cc ^ (row & 7);
        const float* src = Kt + row * DH + c * 8;
        f32x4 a = *(const f32x4*)src;
        f32x4 b = *(const f32x4*)(src + 4);
        bf16x8 o;
        #pragma unroll
        for (int j = 0; j < 4; ++j) { o[j] = (__bf16)a[j]; o[j + 4] = (__bf16)b[j]; }
        *(bf16x8*)&outK[m * 8] = o;
    }
    {
        const int kv = tid >> 2, dq = (tid & 3) * 16;
        const float* src = Vt + kv * DH + dq;
        f32x4 v0 = *(const f32x4*)src,        v1 = *(const f32x4*)(src + 4);
        f32x4 v2 = *(const f32x4*)(src + 8),  v3 = *(const f32x4*)(src + 12);
        bf16x8 o0, o1;
        #pragma unroll
        for (int j = 0; j < 4; ++j) {
            o0[j] = (__bf16)v0[j]; o0[j + 4] = (__bf16)v1[j];
            o1[j] = (__bf16)v2[j]; o1[j + 4] = (__bf16)v3[j];
        }
        *(bf16x8*)&Vtmp[kv * 72 + dq]     = o0;
        *(bf16x8*)&Vtmp[kv * 72 + dq + 8] = o1;
    }
    __syncthreads();
    #pragma unroll
    for (int u = 0; u < 2; ++u) {
        const int m  = tid * 2 + u;
        const int d  = m >> 3, cc = m & 7;
        const int S8 = cc ^ (d & 7);
        const int kc = S8 >> 2, hs = S8 & 3;
        bf16x8 o;
        #pragma unroll
        for (int j = 0; j < 8; ++j) {
            const int kv = (kc * 2 + (j >> 2)) * 16 + hs * 4 + (j & 3);
            o[j] = Vtmp[kv * 72 + d];
        }
        *(bf16x8*)&outV[m * 8] = o;
    }
}

// ---------------------------------------------------------------------------
// Sequential-fold attention: block handles Q-tiles {p, 31-p} as ONE flat
// work list of exactly 33 (q-tile, kv-tile) updates -> uniform iteration
// count across all blocks (no dispatch tail).  Single live softmax state;
// part A's output written mid-kernel.  XCD-aware block remap for L2 reuse.
// ---------------------------------------------------------------------------
__launch_bounds__(256, 4)
__global__ void attn_seq(const float* __restrict__ Qg,
                         float* __restrict__ Og,
                         const __bf16* __restrict__ blob) {
    __shared__ __bf16 Klds[2][4096];
    __shared__ __bf16 Vlds[2][4096];

    // bijective XCD remap (gridDim.x = 1024, 8 XCDs -> 128 contiguous each)
    const int f   = blockIdx.x;
    const int chn = gridDim.x >> 3;
    const int fs  = (f & 7) * chn + (f >> 3);
    const int bh  = fs >> 4;
    const int p   = fs & 15;
    const int qa  = p;                 // first Q-tile (small)
    const int qbg = NT - 1 - p;        // second Q-tile (large)

    const int tid = threadIdx.x;
    const int w   = tid >> 6;
    const int l   = tid & 63;
    const int lo  = l & 15;
    const int hi  = l >> 4;

    const size_t base = (size_t)bh * S_LEN * DH;
    const float* Qb = Qg + base;
    float*       Ob = Og + base;
    const char*  blobB = (const char*)(blob + (size_t)bh * NT * TILE_ELEMS);

    // hoisted swizzled LDS element offsets (same formula for K and V tiles)
    int koff[4][2];
    #pragma unroll
    for (int c = 0; c < 4; ++c) {
        koff[c][0] = swz(c * 16 + lo, hi * 8);
        koff[c][1] = swz(c * 16 + lo, 32 + hi * 8);
    }

    // ---- Q fragments: current (starts as part A) + stashed part B ----
    bf16x8 bq0, bq1, bqB0, bqB1;
    {
        const float* pa = Qb + (size_t)(qa  * QB + w * 16 + lo) * DH + hi * 8;
        const float* pb = Qb + (size_t)(qbg * QB + w * 16 + lo) * DH + hi * 8;
        f32x4 a0 = *(const f32x4*)pa,        a1 = *(const f32x4*)(pa + 4);
        f32x4 a2 = *(const f32x4*)(pa + 32), a3 = *(const f32x4*)(pa + 36);
        f32x4 b0 = *(const f32x4*)pb,        b1 = *(const f32x4*)(pb + 4);
        f32x4 b2 = *(const f32x4*)(pb + 32), b3 = *(const f32x4*)(pb + 36);
        #pragma unroll
        for (int j = 0; j < 4; ++j) {
            bq0[j]  = (__bf16)(a0[j] * 0.125f); bq0[j + 4]  = (__bf16)(a1[j] * 0.125f);
            bq1[j]  = (__bf16)(a2[j] * 0.125f); bq1[j + 4]  = (__bf16)(a3[j] * 0.125f);
            bqB0[j] = (__bf16)(b0[j] * 0.125f); bqB0[j + 4] = (__bf16)(b1[j] * 0.125f);
            bqB1[j] = (__bf16)(b2[j] * 0.125f); bqB1[j + 4] = (__bf16)(b3[j] * 0.125f);
        }
    }

    f32x4 oacc[4];
    #pragma unroll
    for (int n = 0; n < 4; ++n) oacc[n] = (f32x4){0.f, 0.f, 0.f, 0.f};
    float mrow = -1e30f, lrow = 0.f;

    auto stage = [&](int buf, int t) {
        const char* tb = blobB + (size_t)t * TILE_BYTES;
        char* kd = (char*)&Klds[buf][w * 1024];
        char* vd = (char*)&Vlds[buf][w * 1024];
        const char* ks = tb + w * 2048 + l * 16;
        const char* vs = tb + 8192 + w * 2048 + l * 16;
        gl2lds16(ks,        kd);
        gl2lds16(ks + 1024, kd + 1024);
        gl2lds16(vs,        vd);
        gl2lds16(vs + 1024, vd + 1024);
    };

    auto writeO = [&](int qt) {
        const float linv = 1.0f / lrow;
        const int   q    = qt * QB + w * 16 + lo;
        #pragma unroll
        for (int n = 0; n < 4; ++n) {
            f32x4 o;
            #pragma unroll
            for (int r = 0; r < 4; ++r) o[r] = oacc[n][r] * linv;
            *(f32x4*)(Ob + (size_t)q * DH + n * 16 + hi * 4) = o;
        }
    };

    stage(0, 0);                        // tile(0) == 0 for both phases
    __syncthreads();

    for (int u = 0; u <= 32; ++u) {     // 33 uniform iterations
        const int cur = u & 1;
        if (u < 32) {
            const int tn = (u + 1 <= qa) ? (u + 1) : (u - qa);  // tile(u+1)
            stage(cur ^ 1, tn);
        }
        const bool diag = (u == qa) || (u == 32);
        const __bf16* Kc = &Klds[cur][0];
        const __bf16* Vc = &Vlds[cur][0];

        // ---- S^T = K (Q*scale)^T ----
        f32x4 sc[4];
        __builtin_amdgcn_s_setprio(1);
        #pragma unroll
        for (int c = 0; c < 4; ++c) {
            bf16x8 ak0 = *(const bf16x8*)&Kc[koff[c][0]];
            bf16x8 ak1 = *(const bf16x8*)&Kc[koff[c][1]];
            f32x4 acc = (f32x4){0.f, 0.f, 0.f, 0.f};
            acc = __builtin_amdgcn_mfma_f32_16x16x32_bf16(ak0, bq0, acc, 0, 0, 0);
            acc = __builtin_amdgcn_mfma_f32_16x16x32_bf16(ak1, bq1, acc, 0, 0, 0);
            sc[c] = acc;
        }
        __builtin_amdgcn_s_setprio(0);

        // ---- causal mask on diagonal tiles (tile index == q-tile index) ----
        if (diag) {
            const int qloc = w * 16 + lo;
            #pragma unroll
            for (int c = 0; c < 4; ++c)
                #pragma unroll
                for (int r = 0; r < 4; ++r)
                    if (c * 16 + hi * 4 + r > qloc) sc[c][r] = -1e30f;
        }

        // ---- online softmax (lane-local q-column; exp2; T13 defer) ----
        float pm = -1e30f;
        #pragma unroll
        for (int c = 0; c < 4; ++c)
            pm = fmaxf(pm, fmaxf(fmaxf(sc[c][0], sc[c][1]),
                                 fmaxf(sc[c][2], sc[c][3])));
        pm = fmaxf(pm, __shfl_xor(pm, 16, 64));
        pm = fmaxf(pm, __shfl_xor(pm, 32, 64));

        if (!__all(pm - mrow <= 5.545f)) {
            const float mn = fmaxf(mrow, pm);
            const float fr = fexp2((mrow - mn) * L2E);
            mrow = mn; lrow *= fr;
            #pragma unroll
            for (int n = 0; n < 4; ++n) oacc[n] *= fr;
        }
        const float mL = mrow * L2E;
        float rs = 0.f;
        #pragma unroll
        for (int c = 0; c < 4; ++c)
            #pragma unroll
            for (int r = 0; r < 4; ++r) {
                float pe = fexp2(fmaf(sc[c][r], L2E, -mL));
                sc[c][r] = pe;
                rs += pe;
            }
        rs += __shfl_xor(rs, 16, 64);
        rs += __shfl_xor(rs, 32, 64);
        lrow += rs;

        // ---- pack P^T (pi-consistent with V image) ----
        bf16x8 pb[2];
        #pragma unroll
        for (int kc = 0; kc < 2; ++kc)
            #pragma unroll
            for (int j = 0; j < 8; ++j)
                pb[kc][j] = (__bf16)sc[kc * 2 + (j >> 2)][j & 3];

        // ---- O^T += V^T P^T ----
        __builtin_amdgcn_s_setprio(1);
        #pragma unroll
        for (int n = 0; n < 4; ++n) {
            bf16x8 av0 = *(const bf16x8*)&Vc[koff[n][0]];
            bf16x8 av1 = *(const bf16x8*)&Vc[koff[n][1]];
            oacc[n] = __builtin_amdgcn_mfma_f32_16x16x32_bf16(av0, pb[0], oacc[n], 0, 0, 0);
            oacc[n] = __builtin_amdgcn_mfma_f32_16x16x32_bf16(av1, pb[1], oacc[n], 0, 0, 0);
        }
        __builtin_amdgcn_s_setprio(0);

        __syncthreads();                // next tile landed (vmcnt drain) + barrier

        // ---- phase switch: A done -> write O_A, reset state, swap Q ----
        if (u == qa) {
            writeO(qa);
            #pragma unroll
            for (int n = 0; n < 4; ++n) oacc[n] = (f32x4){0.f, 0.f, 0.f, 0.f};
            mrow = -1e30f; lrow = 0.f;
            bq0 = bqB0; bq1 = bqB1;
        }
    }

    writeO(qbg);
}

// ---------------------------------------------------------------------------
// Fallback (R2 kernel): used only if ws_size < 32MB.
// ---------------------------------------------------------------------------
__launch_bounds__(256, 4)
__global__ void attn_fwd(const float* __restrict__ Kg,
                         const float* __restrict__ Qg,
                         const float* __restrict__ Vg,
                         float* __restrict__ Og) {
    __shared__ __bf16 Klds[64 * 64];
    __shared__ __bf16 Vlds[64 * 64];

    const int qb  = blockIdx.x;
    const int bh  = blockIdx.y;
    const int tid = threadIdx.x;
    const int w   = tid >> 6;
    const int l   = tid & 63;
    const int lo  = l & 15;
    const int hi  = l >> 4;

    const int    q0   = qb * QB;
    const size_t base = (size_t)bh * S_LEN * DH;
    const float* Kb = Kg + base;
    const float* Qb = Qg + base;
    const float* Vb = Vg + base;
    float*       Ob = Og + base;

    bf16x8 bq[2];
    {
        const int qrow = q0 + w * 16 + lo;
        #pragma unroll
        for (int dc = 0; dc < 2; ++dc) {
            const float* p = Qb + (size_t)qrow * DH + dc * 32 + hi * 8;
            f32x4 v0 = *(const f32x4*)p;
            f32x4 v1 = *(const f32x4*)(p + 4);
            #pragma unroll
            for (int j = 0; j < 4; ++j) {
                bq[dc][j]     = (__bf16)(v0[j] * 0.125f);
                bq[dc][j + 4] = (__bf16)(v1[j] * 0.125f);
            }
        }
    }

    f32x4 oacc[4];
    #pragma unroll
    for (int n = 0; n < 4; ++n) oacc[n] = (f32x4){0.f, 0.f, 0.f, 0.f};
    float mrow = -1e30f, lrow = 0.f;

    const int krr = tid >> 4;
    const int kc4 = (tid & 15) * 4;

    for (int t = 0; t <= qb; ++t) {
        const int kv0 = t * KVB;
        {
            const float* kp = Kb + (size_t)kv0 * DH + kc4;
            #pragma unroll
            for (int i = 0; i < 4; ++i) {
                const int row = i * 16 + krr;
                f32x4 k4 = *(const f32x4*)(kp + (size_t)row * DH);
                bf16x4 kb;
                #pragma unroll
                for (int j = 0; j < 4; ++j) kb[j] = (__bf16)k4[j];
                *(bf16x4*)&Klds[swz(row, kc4)] = kb;
            }
        }
        {
            const float* vp = Vb + (size_t)kv0 * DH + l;
            float vv[16];
            #pragma unroll
            for (int i = 0; i < 16; ++i) {
                const int s  = w * 16 + i;
                const int kc = s >> 5, hs = (s >> 3) & 3, j = s & 7;
                const int kv = (kc * 2 + (j >> 2)) * 16 + hs * 4 + (j & 3);
                vv[i] = vp[(size_t)kv * DH];
            }
            bf16x8 v0, v1;
            #pragma unroll
            for (int i = 0; i < 8; ++i) { v0[i] = (__bf16)vv[i]; v1[i] = (__bf16)vv[8 + i]; }
            *(bf16x8*)&Vlds[swz(l, w * 16)]     = v0;
            *(bf16x8*)&Vlds[swz(l, w * 16 + 8)] = v1;
        }
        __syncthreads();

        const bool diag = (t == qb);
        const int  cmax = diag ? (w + 1) : 4;
        f32x4 sc[4];
        #pragma unroll
        for (int c = 0; c < 4; ++c) {
            if (c < cmax) {
                f32x4 acc = (f32x4){0.f, 0.f, 0.f, 0.f};
                #pragma unroll
                for (int dc = 0; dc < 2; ++dc) {
                    bf16x8 ak = *(const bf16x8*)&Klds[swz(c * 16 + lo, dc * 32 + hi * 8)];
                    acc = __builtin_amdgcn_mfma_f32_16x16x32_bf16(ak, bq[dc], acc, 0, 0, 0);
                }
                sc[c] = acc;
            } else {
                sc[c] = (f32x4){-1e30f, -1e30f, -1e30f, -1e30f};
            }
        }
        if (diag) {
            #pragma unroll
            for (int r = 0; r < 4; ++r)
                if (hi * 4 + r > lo) sc[w][r] = -1e30f;
        }

        float pm = -1e30f;
        #pragma unroll
        for (int c = 0; c < 4; ++c)
            #pragma unroll
            for (int r = 0; r < 4; ++r) pm = fmaxf(pm, sc[c][r]);
        pm = fmaxf(pm, __shfl_xor(pm, 16, 64));
        pm = fmaxf(pm, __shfl_xor(pm, 32, 64));

        const float mn = fmaxf(mrow, pm);
        const float fr = __expf(mrow - mn);
        mrow = mn;
        float rs = 0.f;
        #pragma unroll
        for (int c = 0; c < 4; ++c)
            #pragma unroll
            for (int r = 0; r < 4; ++r) {
                float pe = __expf(sc[c][r] - mn);
                sc[c][r] = pe;
                rs += pe;
            }
        rs += __shfl_xor(rs, 16, 64);
        rs += __shfl_xor(rs, 32, 64);
        lrow = lrow * fr + rs;
        #pragma unroll
        for (int n = 0; n < 4; ++n) oacc[n] *= fr;

        bf16x8 pb[2];
        #pragma unroll
        for (int kc = 0; kc < 2; ++kc)
            #pragma unroll
            for (int j = 0; j < 8; ++j)
                pb[kc][j] = (__bf16)sc[kc * 2 + (j >> 2)][j & 3];

        #pragma unroll
        for (int n = 0; n < 4; ++n) {
            #pragma unroll
            for (int kc = 0; kc < 2; ++kc) {
                bf16x8 av = *(const bf16x8*)&Vlds[swz(n * 16 + lo, kc * 32 + hi * 8)];
                oacc[n] = __builtin_amdgcn_mfma_f32_16x16x32_bf16(av, pb[kc], oacc[n], 0, 0, 0);
            }
        }
        __syncthreads();
    }

    const float linv = 1.0f / lrow;
    const int   q    = q0 + w * 16 + lo;
    #pragma unroll
    for (int n = 0; n < 4; ++n) {
        f32x4 o;
        #pragma unroll
        for (int r = 0; r < 4; ++r) o[r] = oacc[n][r] * linv;
        *(f32x4*)(Ob + (size_t)q * DH + n * 16 + hi * 4) = o;
    }
}

extern "C" void kernel_launch(void* const* d_in, const int* in_sizes, int n_in,
                              void* d_out, int out_size, void* d_ws, size_t ws_size,
                              hipStream_t stream) {
    const float* keys    = (const float*)d_in[0];
    const float* queries = (const float*)d_in[1];
    const float* values  = (const float*)d_in[2];
    float* out = (float*)d_out;

    const int    BH   = in_sizes[0] / (S_LEN * DH);          // B*H = 64
    const size_t need = (size_t)BH * NT * TILE_BYTES;        // 32 MB
    const int    nblk = (NT / 2) * BH;                       // 1024

    if (ws_size >= need && (nblk % 8) == 0) {
        prep_kv<<<dim3(BH * NT), 256, 0, stream>>>(keys, values, (__bf16*)d_ws);
        attn_seq<<<dim3(nblk), 256, 0, stream>>>(queries, out,
                                                 (const __bf16*)d_ws);
    } else {
        attn_fwd<<<dim3(S_LEN / QB, BH), 256, 0, stream>>>(keys, queries, values, out);
    }
}